// Round 5
// baseline (551.118 us; speedup 1.0000x reference)
//
#include <hip/hip_runtime.h>
#include <hip/hip_bf16.h>

#define B_ 64
#define T_ 128
#define E_ 256
#define H_ 256
#define OW_ 512   // output row width = 2*H (elements)
#define LP 264    // LDS row pitch in bf16 elements (256 + 8 pad -> spreads banks)

typedef unsigned short ushort_t;
typedef __attribute__((ext_vector_type(8))) short bf16x8;   // 8 bf16 = 4 VGPRs
typedef __attribute__((ext_vector_type(4))) float f32x4;    // 4 f32 acc

__device__ __forceinline__ float bf2f(ushort_t u) {
    return __uint_as_float(((unsigned int)u) << 16);
}
__device__ __forceinline__ ushort_t f2bf(float f) {
    unsigned int x = __float_as_uint(f);
    unsigned int r = x + 0x7FFFu + ((x >> 16) & 1u);
    return (ushort_t)(r >> 16);
}
__device__ __forceinline__ float fast_tanh(float x) {
    // tanh(x) = 1 - 2/(exp(2x)+1); finite for all finite x (overflow -> +-1)
    float e = __expf(2.0f * x);
    return 1.0f - 2.0f * __builtin_amdgcn_rcpf(e + 1.0f);
}

// Runtime dtype detection (validated rounds 3-4): mask0 is exactly {0.0,1.0}.
// f32 words are only 0x00000000/0x3F800000; bf16-pair words also produce
// 0x00003F80/0x3F803F80 (p=1/4 each). P(misclassify bf16) = 2^-64.
__device__ __forceinline__ int detect_bf16(const unsigned int* probe, int tid,
                                           int* flag_s) {
    unsigned int w = probe[tid & 63];
    unsigned long long vote = __ballot(w == 0x00003F80u || w == 0x3F803F80u);
    if (tid == 0) *flag_s = (vote != 0ull) ? 1 : 0;
    __syncthreads();
    return *flag_s;
}

__device__ __forceinline__ float loadF(const void* p, size_t i, int isbf) {
    return isbf ? bf2f(((const ushort_t*)p)[i]) : ((const float*)p)[i];
}
__device__ __forceinline__ void storeF(void* p, size_t i, int isbf, float v) {
    if (isbf) ((ushort_t*)p)[i] = f2bf(v);
    else      ((float*)p)[i] = v;
}

// Load one B-fragment (8 contiguous weights W[flat base..+7], optional *mask)
// as bf16x8. bf16 path: uint4 load + bitwise mask-select (mask is {0,1} so
// result is exact). f32 path: scalar loads + round to bf16.
__device__ __forceinline__ bf16x8 load_bfrag(const void* W, const void* M,
                                             size_t base, int isbf) {
    union { bf16x8 v; ushort_t u[8]; } r;
    if (isbf) {
        union { uint4 q; ushort_t u[8]; } wv, mv;
        wv.q = *(const uint4*)((const ushort_t*)W + base);
        if (M) {
            mv.q = *(const uint4*)((const ushort_t*)M + base);
            #pragma unroll
            for (int j = 0; j < 8; ++j)
                wv.u[j] = (mv.u[j] == 0x3F80u) ? wv.u[j] : (ushort_t)0;
        }
        #pragma unroll
        for (int j = 0; j < 8; ++j) r.u[j] = wv.u[j];
    } else {
        #pragma unroll
        for (int j = 0; j < 8; ++j) {
            float v = ((const float*)W)[base + j];
            if (M) v *= ((const float*)M)[base + j];
            r.u[j] = f2bf(v);
        }
    }
    return r.v;
}

// Load 8 elements (generic dtype) -> packed bf16 x8 (for LDS staging).
__device__ __forceinline__ uint4 load8_pack(const void* src, size_t idx, int isbf) {
    union { uint4 q; ushort_t u[8]; } t;
    if (isbf) {
        t.q = *(const uint4*)((const ushort_t*)src + idx);
    } else {
        const float* f = (const float*)src + idx;
        #pragma unroll
        for (int j = 0; j < 8; ++j) t.u[j] = f2bf(f[j]);
    }
    return t.q;
}

// ---------------------------------------------------------------------------
// Scan: 4 WGs x 16 batch rows, 512 threads (8 waves). Wave wv owns cols
// [wv*32, wv*32+32) as 2 MFMA col-tiles; masked W_rec B-fragments live in
// 64 VGPRs for the whole time loop. h (bf16) double-buffered in LDS,
// [16][LP]. MFMA 16x16x32: A[m=lane&15][k=quad*8+j], B[k][n=lane&15],
// C/D[row=quad*4+reg][col=lane&15] (guide-verified layouts).
// xp prefetched one step ahead; same-lane read-then-write ordering makes the
// scan1 xp/hout alias (both col H_) safe.
// ---------------------------------------------------------------------------
__global__ __launch_bounds__(512, 2)
void ltc_scan_mfma(void* base, int xp_col, int out_col,
                   const void* __restrict__ Wrec,
                   const void* __restrict__ mask,
                   const void* __restrict__ tau_raw,
                   const unsigned int* __restrict__ probe)
{
    const int tid  = threadIdx.x;
    const int lane = tid & 63;
    const int wv   = tid >> 6;     // 0..7
    const int quad = lane >> 4;    // 0..3
    const int l15  = lane & 15;

    __shared__ __align__(16) ushort_t hbuf[2][16][LP];
    __shared__ int flag_s;
    const int isbf = detect_bf16(probe, tid, &flag_s);

    // B fragments: Wrec*mask, 2 col-tiles x 8 K-chunks
    bf16x8 Bf[2][8];
    const int n0 = wv * 32;
    #pragma unroll
    for (int tc = 0; tc < 2; ++tc) {
        const int n = n0 + tc * 16 + l15;
        #pragma unroll
        for (int kk = 0; kk < 8; ++kk)
            Bf[tc][kk] = load_bfrag(Wrec, mask,
                                    (size_t)n * H_ + kk * 32 + quad * 8, isbf);
    }

    // Per-lane epilogue state: (row r=quad*4+reg, col c=n0+tc*16+l15)
    const int bg = blockIdx.x * 16;          // batch group start
    float inv_tau[2], h_prev[2][4], xp_cur[2][4];
    #pragma unroll
    for (int tc = 0; tc < 2; ++tc) {
        const int c = n0 + tc * 16 + l15;
        const float tr = loadF(tau_raw, c, isbf);
        inv_tau[tc] = 1.0f / (logf(1.0f + __expf(tr)) + 0.1f);
        #pragma unroll
        for (int reg = 0; reg < 4; ++reg) {
            h_prev[tc][reg] = 0.0f;
            const int b = bg + quad * 4 + reg;
            xp_cur[tc][reg] = loadF(base, (size_t)b * T_ * OW_ + xp_col + c, isbf);
        }
    }

    // zero h buffer 0 (16*LP ushorts = 2112 uints)
    for (int i = tid; i < 16 * LP / 2; i += 512)
        ((unsigned int*)&hbuf[0][0][0])[i] = 0u;
    __syncthreads();

    for (int t = 0; t < T_; ++t) {
        const int rb = t & 1;

        // A fragments: h[l15][kk*32 + quad*8 ..+7] (16B-aligned, padded pitch)
        bf16x8 Af[8];
        #pragma unroll
        for (int kk = 0; kk < 8; ++kk)
            Af[kk] = *(const bf16x8*)&hbuf[rb][l15][kk * 32 + quad * 8];

        f32x4 acc0 = {0.f, 0.f, 0.f, 0.f};
        f32x4 acc1 = {0.f, 0.f, 0.f, 0.f};
        #pragma unroll
        for (int kk = 0; kk < 8; ++kk) {
            acc0 = __builtin_amdgcn_mfma_f32_16x16x32_bf16(Af[kk], Bf[0][kk], acc0, 0, 0, 0);
            acc1 = __builtin_amdgcn_mfma_f32_16x16x32_bf16(Af[kk], Bf[1][kk], acc1, 0, 0, 0);
        }

        #pragma unroll
        for (int tc = 0; tc < 2; ++tc) {
            const int c = n0 + tc * 16 + l15;
            #pragma unroll
            for (int reg = 0; reg < 4; ++reg) {
                const int r = quad * 4 + reg;
                const int b = bg + r;
                const float pre = xp_cur[tc][reg] + (tc ? acc1[reg] : acc0[reg]);
                const float hn  = h_prev[tc][reg]
                                + (fast_tanh(pre) - h_prev[tc][reg]) * inv_tau[tc];
                h_prev[tc][reg] = hn;
                hbuf[rb ^ 1][r][c] = f2bf(hn);
                storeF(base, ((size_t)b * T_ + t) * OW_ + out_col + c, isbf, hn);
                if (t + 1 < T_)   // prefetch next xp (same-lane alias ordering)
                    xp_cur[tc][reg] =
                        loadF(base, ((size_t)b * T_ + (t + 1)) * OW_ + xp_col + c, isbf);
            }
        }
        __syncthreads();
    }
}

// ---------------------------------------------------------------------------
// Proj: dst[r][dst_col+n] = bias[n] + sum_k src_row(r)[k] * Wi[n][k]
// 256 WGs x 32 rows, 1024 threads (16 waves). Wave wv owns col-tile wv
// (B-frags in 32 VGPRs); 32 rows staged once into LDS as bf16; 2 row-tiles
// of 8 MFMA each; bias folded into C init.
// ---------------------------------------------------------------------------
__global__ __launch_bounds__(1024, 4)
void proj_mfma(const void* src, int src_stride, int src_col,
               const int* __restrict__ tok,
               const void* __restrict__ Wi,
               const void* __restrict__ bias,
               void* dst, int dst_col,
               const unsigned int* __restrict__ probe)
{
    const int tid  = threadIdx.x;
    const int lane = tid & 63;
    const int wv   = tid >> 6;     // 0..15 -> col tile
    const int quad = lane >> 4;
    const int l15  = lane & 15;

    __shared__ __align__(16) ushort_t As[32][LP];
    __shared__ int flag_s;
    const int isbf = detect_bf16(probe, tid, &flag_s);

    bf16x8 Bf[8];
    const int n0 = wv * 16;
    #pragma unroll
    for (int kk = 0; kk < 8; ++kk)
        Bf[kk] = load_bfrag(Wi, nullptr,
                            (size_t)(n0 + l15) * H_ + kk * 32 + quad * 8, isbf);
    const float bj = loadF(bias, n0 + l15, isbf);

    const int r0 = blockIdx.x * 32;

    // stage 32 rows x 256 elems = 1024 chunks of 8 -> exactly 1 per thread
    {
        const int row  = tid >> 5;
        const int off8 = (tid & 31) * 8;
        const size_t sb = (tok ? (size_t)tok[r0 + row] * src_stride
                               : (size_t)(r0 + row) * src_stride) + src_col + off8;
        *(uint4*)&As[row][off8] = load8_pack(src, sb, isbf);
    }
    __syncthreads();

    #pragma unroll
    for (int rt = 0; rt < 2; ++rt) {
        bf16x8 Af[8];
        #pragma unroll
        for (int kk = 0; kk < 8; ++kk)
            Af[kk] = *(const bf16x8*)&As[rt * 16 + l15][kk * 32 + quad * 8];

        f32x4 acc = {bj, bj, bj, bj};
        #pragma unroll
        for (int kk = 0; kk < 8; ++kk)
            acc = __builtin_amdgcn_mfma_f32_16x16x32_bf16(Af[kk], Bf[kk], acc, 0, 0, 0);

        #pragma unroll
        for (int reg = 0; reg < 4; ++reg) {
            const int r = r0 + rt * 16 + quad * 4 + reg;
            storeF(dst, (size_t)r * OW_ + dst_col + n0 + l15, isbf, acc[reg]);
        }
    }
}

extern "C" void kernel_launch(void* const* d_in, const int* in_sizes, int n_in,
                              void* d_out, int out_size, void* d_ws, size_t ws_size,
                              hipStream_t stream)
{
    const int* tokens = (const int*)d_in[0];
    const void* emb    = d_in[1];
    const void* W_in0  = d_in[2];
    const void* W_rec0 = d_in[3];
    const void* b0     = d_in[4];
    const void* tau0   = d_in[5];
    const void* mask0  = d_in[6];
    const void* W_in1  = d_in[7];
    const void* W_rec1 = d_in[8];
    const void* b1     = d_in[9];
    const void* tau1   = d_in[10];
    const void* mask1  = d_in[11];
    const unsigned int* probe = (const unsigned int*)mask0;
    (void)d_ws; (void)ws_size; (void)in_sizes; (void)n_in; (void)out_size;

    const int R = B_ * T_;  // 8192

    // d_out = [8192, 512] elements (dtype detected on device).
    // cols 0..255: h0 (final L0 output). cols 256..511: xp scratch, then h1.
    proj_mfma<<<dim3(R / 32), dim3(1024), 0, stream>>>(
        emb, E_, 0, tokens, W_in0, b0, d_out, H_, probe);
    ltc_scan_mfma<<<dim3(B_ / 16), dim3(512), 0, stream>>>(
        d_out, H_, 0, W_rec0, mask0, tau0, probe);
    proj_mfma<<<dim3(R / 32), dim3(1024), 0, stream>>>(
        d_out, OW_, 0, nullptr, W_in1, b1, d_out, H_, probe);
    ltc_scan_mfma<<<dim3(B_ / 16), dim3(512), 0, stream>>>(
        d_out, H_, H_, W_rec1, mask1, tau1, probe);
}

// Round 7
// 474.149 us; speedup vs baseline: 1.1623x; 1.1623x over previous
//
#include <hip/hip_runtime.h>
#include <hip/hip_bf16.h>

#define B_ 64
#define T_ 128
#define E_ 256
#define H_ 256
#define OW_ 512   // output row width = 2*H (elements)
#define LP 264    // LDS bf16 row pitch (elements)
#define LPF 264   // LDS f32 row pitch (elements)

typedef unsigned short ushort_t;
typedef __attribute__((ext_vector_type(8))) short bf16x8;   // 8 bf16 = 4 VGPRs
typedef __attribute__((ext_vector_type(4))) float f32x4;    // 4 f32 acc

// Workgroup barrier WITHOUT the compiler's vmcnt(0) drain: only LDS (lgkm)
// ordering is required at our per-step barriers; global loads/stores stay in
// flight across steps. "memory" clobber pins memory ops on their side.
#define LGKM_BARRIER() asm volatile("s_waitcnt lgkmcnt(0)\n\ts_barrier" ::: "memory")

__device__ __forceinline__ ushort_t f2bf(float f) {
    unsigned int x = __float_as_uint(f);
    unsigned int r = x + 0x7FFFu + ((x >> 16) & 1u);
    return (ushort_t)(r >> 16);
}
__device__ __forceinline__ float fast_tanh(float x) {
    // tanh(x) = 1 - 2/(exp(2x)+1); finite for all finite x (overflow -> +-1)
    float e = __expf(2.0f * x);
    return 1.0f - 2.0f * __builtin_amdgcn_rcpf(e + 1.0f);
}

// B-fragment from f32 weights (optional f32 {0,1} mask), rounded to bf16.
__device__ __forceinline__ bf16x8 load_bfrag(const float* W, const float* M,
                                             size_t base) {
    union { bf16x8 v; ushort_t u[8]; } r;
    #pragma unroll
    for (int j = 0; j < 8; ++j) {
        float v = W[base + j];
        if (M) v *= M[base + j];
        r.u[j] = f2bf(v);
    }
    return r.v;
}

// ---------------------------------------------------------------------------
// Scan: 4 WGs x 16 batch rows, 512 threads (8 waves). Wave wv owns 32 cols
// (2 MFMA col-tiles); masked W_rec B-frags resident in registers (MFMA reads
// A/B from AGPRs natively, so AGPR offload is harmless).
// h kept two ways in LDS, both double-buffered: bf16 copy (MFMA A-frags) and
// f32 copy (wide contiguous output stores). Per step: wide-store h(t-1)
// (ds b128 -> 2x global dwordx4, 1KB-contiguous rows), prefetch xp(t+1),
// 8 ds_read_b128 A-frags, 16 MFMA, epilogue (8 tanh/lane), lgkm-only barrier.
// MFMA 16x16x32 layouts (verified r5): A[m=l15][k=quad*8+j], B[k][n=l15],
// C/D[row=quad*4+reg][col=l15].
// scan1 aliases xp and out regions (both col H_): accesses are row-disjoint
// (store row t-1, load row t+1); the load is consumed before the barrier
// preceding the store that overwrites it.
// ---------------------------------------------------------------------------
__global__ __launch_bounds__(512, 2)
void ltc_scan_mfma(float* base, int xp_col, int out_col,
                   const float* __restrict__ Wrec,
                   const float* __restrict__ mask,
                   const float* __restrict__ tau_raw)
{
    const int tid  = threadIdx.x;
    const int lane = tid & 63;
    const int wv   = tid >> 6;     // 0..7
    const int quad = lane >> 4;    // 0..3
    const int l15  = lane & 15;

    __shared__ __align__(16) ushort_t hb16[2][16][LP];
    __shared__ __align__(16) float    hf32[2][16][LPF];

    // --- B fragments: bf16(Wrec * mask) ---
    bf16x8 Bf[2][8];
    const int n0 = wv * 32;
    #pragma unroll
    for (int tc = 0; tc < 2; ++tc) {
        const int n = n0 + tc * 16 + l15;
        #pragma unroll
        for (int kk = 0; kk < 8; ++kk)
            Bf[tc][kk] = load_bfrag(Wrec, mask,
                                    (size_t)n * H_ + kk * 32 + quad * 8);
    }

    // --- per-lane epilogue state: (batch b = bg+quad*4+reg, col c) ---
    const int bg = blockIdx.x * 16;
    float inv_tau[2], h_prev[2][4], xp_cur[2][4], xp_nxt[2][4];
    unsigned int xoff[2][4];          // element offsets, advance OW_ per step
    #pragma unroll
    for (int tc = 0; tc < 2; ++tc) {
        const int c = n0 + tc * 16 + l15;
        inv_tau[tc] = 1.0f / (logf(1.0f + __expf(tau_raw[c])) + 0.1f);
        #pragma unroll
        for (int reg = 0; reg < 4; ++reg) {
            const int b = bg + quad * 4 + reg;
            h_prev[tc][reg] = 0.0f;
            unsigned int o = (unsigned int)(b * T_) * OW_ + xp_col + c;
            xp_cur[tc][reg] = base[o];
            xoff[tc][reg]   = o + OW_;            // -> row t=1
            xp_nxt[tc][reg] = 0.0f;
        }
    }

    // --- wide-store lane mapping: thread -> (batch row, 8-elem chunk) ---
    const int b_loc = tid >> 5;           // 0..15
    const int chunk = tid & 31;           // 0..31
    unsigned int ooff = (unsigned int)((bg + b_loc) * T_) * OW_
                        + out_col + chunk * 8;      // row 0 (elements)

    // zero bf16 h buffer 0 (h(-1) = 0): 16*LP ushorts = 2112 uints
    for (int i = tid; i < 16 * LP / 2; i += 512)
        ((unsigned int*)&hb16[0][0][0])[i] = 0u;
    __syncthreads();   // full barrier once (prologue)

    for (int t = 0; t < T_; ++t) {
        const int rb = t & 1;   // buffers [rb] hold h(t-1)

        // 1) wide store of h(t-1): contiguous 1KB per batch row (f32)
        if (t > 0) {
            float4 h0 = *(const float4*)&hf32[rb][b_loc][chunk * 8];
            float4 h1 = *(const float4*)&hf32[rb][b_loc][chunk * 8 + 4];
            *(float4*)(base + ooff)     = h0;
            *(float4*)(base + ooff + 4) = h1;
            ooff += OW_;
        }

        // 2) prefetch xp(t+1)
        if (t + 1 < T_) {
            #pragma unroll
            for (int tc = 0; tc < 2; ++tc)
                #pragma unroll
                for (int reg = 0; reg < 4; ++reg) {
                    xp_nxt[tc][reg] = base[xoff[tc][reg]];
                    xoff[tc][reg] += OW_;
                }
        }

        // 3) A fragments from LDS (bf16 copy of h(t-1))
        bf16x8 Af[8];
        #pragma unroll
        for (int kk = 0; kk < 8; ++kk)
            Af[kk] = *(const bf16x8*)&hb16[rb][l15][kk * 32 + quad * 8];

        // 4) MFMA
        f32x4 acc0 = {0.f, 0.f, 0.f, 0.f};
        f32x4 acc1 = {0.f, 0.f, 0.f, 0.f};
        #pragma unroll
        for (int kk = 0; kk < 8; ++kk) {
            acc0 = __builtin_amdgcn_mfma_f32_16x16x32_bf16(Af[kk], Bf[0][kk], acc0, 0, 0, 0);
            acc1 = __builtin_amdgcn_mfma_f32_16x16x32_bf16(Af[kk], Bf[1][kk], acc1, 0, 0, 0);
        }

        // 5) epilogue: h update; write h(t) to buffers [rb^1] (bf16 + f32)
        #pragma unroll
        for (int tc = 0; tc < 2; ++tc) {
            const int c = n0 + tc * 16 + l15;
            #pragma unroll
            for (int reg = 0; reg < 4; ++reg) {
                const int r = quad * 4 + reg;
                const float a   = (tc == 0) ? acc0[reg] : acc1[reg];
                const float pre = xp_cur[tc][reg] + a;
                const float hn  = h_prev[tc][reg]
                                + (fast_tanh(pre) - h_prev[tc][reg]) * inv_tau[tc];
                h_prev[tc][reg] = hn;
                hb16[rb ^ 1][r][c] = f2bf(hn);
                hf32[rb ^ 1][r][c] = hn;
                xp_cur[tc][reg] = xp_nxt[tc][reg];
            }
        }
        LGKM_BARRIER();
    }
    // post-loop: store h(T-1) (lives in buffers [T_ & 1])
    {
        float4 h0 = *(const float4*)&hf32[T_ & 1][b_loc][chunk * 8];
        float4 h1 = *(const float4*)&hf32[T_ & 1][b_loc][chunk * 8 + 4];
        *(float4*)(base + ooff)     = h0;
        *(float4*)(base + ooff + 4) = h1;
    }
}

// ---------------------------------------------------------------------------
// Proj: dst[r][dst_col+n] = bias[n] + sum_k src_row(r)[k] * Wi[n][k]
// 256 WGs x 32 rows, 1024 threads (16 waves). f32 rows staged to LDS as bf16
// (32B contiguous loads/thread); B-frags bf16 in registers; MFMA; C
// transposed through f32 LDS for contiguous 32B/thread stores.
// ---------------------------------------------------------------------------
__global__ __launch_bounds__(1024, 2)
void proj_mfma(const float* __restrict__ src, int src_stride,
               const int* __restrict__ tok,
               const float* __restrict__ Wi,
               const float* __restrict__ bias,
               float* __restrict__ dst, int dst_col)
{
    const int tid  = threadIdx.x;
    const int lane = tid & 63;
    const int wvi  = tid >> 6;     // 0..15 -> col tile
    const int quad = lane >> 4;
    const int l15  = lane & 15;

    __shared__ __align__(16) ushort_t As[32][LP];    // bf16 A staging
    __shared__ __align__(16) float    Cs[32][LPF];   // f32 C for wide stores

    bf16x8 Bf[8];
    const int n0 = wvi * 16;
    #pragma unroll
    for (int kk = 0; kk < 8; ++kk)
        Bf[kk] = load_bfrag(Wi, nullptr,
                            (size_t)(n0 + l15) * H_ + kk * 32 + quad * 8);
    const float bj = bias[n0 + l15];

    const int r0  = blockIdx.x * 32;
    const int row = tid >> 5;          // 0..31
    const int seg = tid & 31;          // 8-float chunk

    // stage 32 rows: each thread loads 8 f32 (2x dwordx4), packs to bf16
    {
        const size_t sb = (tok ? (size_t)tok[r0 + row] : (size_t)(r0 + row))
                          * src_stride + seg * 8;
        float4 f0 = *(const float4*)(src + sb);
        float4 f1 = *(const float4*)(src + sb + 4);
        union { uint4 q; ushort_t u[8]; } p;
        p.u[0] = f2bf(f0.x); p.u[1] = f2bf(f0.y);
        p.u[2] = f2bf(f0.z); p.u[3] = f2bf(f0.w);
        p.u[4] = f2bf(f1.x); p.u[5] = f2bf(f1.y);
        p.u[6] = f2bf(f1.z); p.u[7] = f2bf(f1.w);
        *(uint4*)&As[row][seg * 8] = p.q;
    }
    __syncthreads();

    bf16x8 Af[2][8];
    #pragma unroll
    for (int rt = 0; rt < 2; ++rt)
        #pragma unroll
        for (int kk = 0; kk < 8; ++kk)
            Af[rt][kk] = *(const bf16x8*)&As[rt * 16 + l15][kk * 32 + quad * 8];

    f32x4 acc[2] = {{bj, bj, bj, bj}, {bj, bj, bj, bj}};
    #pragma unroll
    for (int rt = 0; rt < 2; ++rt)
        #pragma unroll
        for (int kk = 0; kk < 8; ++kk)
            acc[rt] = __builtin_amdgcn_mfma_f32_16x16x32_bf16(Af[rt][kk], Bf[kk], acc[rt], 0, 0, 0);

    // transpose C through LDS (no barrier needed before: Cs untouched so far)
    #pragma unroll
    for (int rt = 0; rt < 2; ++rt)
        #pragma unroll
        for (int reg = 0; reg < 4; ++reg)
            Cs[rt * 16 + quad * 4 + reg][n0 + l15] = acc[rt][reg];
    __syncthreads();

    // contiguous wide store: 1KB per output row, 32B per thread
    {
        float4 c0 = *(const float4*)&Cs[row][seg * 8];
        float4 c1 = *(const float4*)&Cs[row][seg * 8 + 4];
        float* dp = dst + (size_t)(r0 + row) * OW_ + dst_col + seg * 8;
        *(float4*)dp       = c0;
        *(float4*)(dp + 4) = c1;
    }
}

extern "C" void kernel_launch(void* const* d_in, const int* in_sizes, int n_in,
                              void* d_out, int out_size, void* d_ws, size_t ws_size,
                              hipStream_t stream)
{
    const int*   tokens = (const int*)d_in[0];
    const float* emb    = (const float*)d_in[1];
    const float* W_in0  = (const float*)d_in[2];
    const float* W_rec0 = (const float*)d_in[3];
    const float* b0     = (const float*)d_in[4];
    const float* tau0   = (const float*)d_in[5];
    const float* mask0  = (const float*)d_in[6];
    const float* W_in1  = (const float*)d_in[7];
    const float* W_rec1 = (const float*)d_in[8];
    const float* b1     = (const float*)d_in[9];
    const float* tau1   = (const float*)d_in[10];
    const float* mask1  = (const float*)d_in[11];
    float* out = (float*)d_out;    // [8192, 512] f32
    (void)d_ws; (void)ws_size; (void)in_sizes; (void)n_in; (void)out_size;

    // cols 0..255: h0 (final L0 output). cols 256..511: xp scratch, then h1.
    proj_mfma<<<dim3(256), dim3(1024), 0, stream>>>(emb, E_, tokens, W_in0, b0, out, H_);
    ltc_scan_mfma<<<dim3(4), dim3(512), 0, stream>>>(out, H_, 0, W_rec0, mask0, tau0);
    proj_mfma<<<dim3(256), dim3(1024), 0, stream>>>(out, OW_, nullptr, W_in1, b1, out, H_);
    ltc_scan_mfma<<<dim3(4), dim3(512), 0, stream>>>(out, H_, H_, W_rec1, mask1, tau1);
}

// Round 8
// 409.906 us; speedup vs baseline: 1.3445x; 1.1567x over previous
//
#include <hip/hip_runtime.h>
#include <hip/hip_bf16.h>

#define B_ 64
#define T_ 128
#define E_ 256
#define H_ 256
#define OW_ 512   // output row width = 2*H (elements)
#define LP 264    // LDS bf16 row pitch (elements)

typedef unsigned short ushort_t;
typedef __attribute__((ext_vector_type(8))) short bf16x8;   // 8 bf16 = 4 VGPRs
typedef __attribute__((ext_vector_type(4))) float f32x4;    // 4 f32 acc

// Workgroup barrier WITHOUT the compiler's vmcnt(0) drain: only LDS (lgkm)
// ordering is required at our per-step barriers; global loads/stores stay in
// flight across steps. (Validated round 7.)
#define LGKM_BARRIER() asm volatile("s_waitcnt lgkmcnt(0)\n\ts_barrier" ::: "memory")

__device__ __forceinline__ ushort_t f2bf(float f) {
    unsigned int x = __float_as_uint(f);
    unsigned int r = x + 0x7FFFu + ((x >> 16) & 1u);
    return (ushort_t)(r >> 16);
}
__device__ __forceinline__ float fast_tanh(float x) {
    // tanh(x) = 1 - 2/(exp(2x)+1); finite for all finite x (overflow -> +-1)
    float e = __expf(2.0f * x);
    return 1.0f - 2.0f * __builtin_amdgcn_rcpf(e + 1.0f);
}

// 8 contiguous f32 weights (optional f32 {0,1} mask) -> bf16x8 fragment.
__device__ __forceinline__ bf16x8 load_bfrag(const float* W, const float* M,
                                             size_t base) {
    float4 a = *(const float4*)(W + base);
    float4 b = *(const float4*)(W + base + 4);
    if (M) {
        float4 ma = *(const float4*)(M + base);
        float4 mb = *(const float4*)(M + base + 4);
        a.x *= ma.x; a.y *= ma.y; a.z *= ma.z; a.w *= ma.w;
        b.x *= mb.x; b.y *= mb.y; b.z *= mb.z; b.w *= mb.w;
    }
    union { bf16x8 v; ushort_t u[8]; } r;
    r.u[0] = f2bf(a.x); r.u[1] = f2bf(a.y); r.u[2] = f2bf(a.z); r.u[3] = f2bf(a.w);
    r.u[4] = f2bf(b.x); r.u[5] = f2bf(b.y); r.u[6] = f2bf(b.z); r.u[7] = f2bf(b.w);
    return r.v;
}

// ---------------------------------------------------------------------------
// Scan: 8 WGs x 8 batch rows, 256 threads (4 waves). Wave wv owns 64 cols
// (4 MFMA col-tiles); masked W_rec B-frags (and optionally W_in1 B2-frags for
// the fused xp1 projection) resident in the unified VGPR/AGPR file
// (__launch_bounds__(256,1) -> 512-reg budget).
// Batch row i (0..7) lives at A-slot (i/2)*4 + (i%2) = {0,1,4,5,8,9,12,13},
// so C rows quad*4+reg with reg<2 are real -> every lane owns exactly
// (4 tiles x 2 regs) = 8 outputs: b = bg + quad*2 + reg, c = n0+tc*16+l15.
// A-slots {2,3,6,7,...} are zeroed once and never written (zero rows of A
// only affect zero rows of C - harmless).
// Per step: 8 ds_read_b128 A-frags, 32 MFMA (+32 fused), epilogue
// (8 tanh/lane), 8 b16 LDS writes, scatter global stores (TA pipe, never
// awaited at the lgkm-only barrier).
// Fused xp1: A-frags at step t are h0(t-1) -> xp1(t-1) = h0(t-1) @ W_in1^T
// + b1 with the SAME A-frags; loop runs T_+1 iterations (last = fused tail).
// MFMA 16x16x32 layouts (verified r5/r7): A[m=l15][k=quad*8+j], B[k][n=l15],
// C/D[row=quad*4+reg][col=l15].
// Unfused scan1 aliases xp and hout (same region): same-lane load(b,t,c) is
// consumed before store(b,t,c) in program order -> safe (validated r7).
// ---------------------------------------------------------------------------
__global__ __launch_bounds__(256, 1)
void ltc_scan_mfma(const float* __restrict__ xp, int xp_stride, int xp_col,
                   float* __restrict__ hout, int out_stride, int out_col,
                   const float* __restrict__ Wrec,
                   const float* __restrict__ mask,
                   const float* __restrict__ tau_raw,
                   const float* Wf,      // W_in1 for fused xp1, or null
                   const float* bf,      // b1 (fused) or null
                   float* xf)            // fused xp1 out [B,T,H], or null
{
    const int tid  = threadIdx.x;
    const int lane = tid & 63;
    const int wv   = tid >> 6;     // 0..3
    const int quad = lane >> 4;    // 0..3
    const int l15  = lane & 15;
    const int n0   = wv * 64;

    __shared__ __align__(16) ushort_t hb16[2][16][LP];

    // --- B fragments: bf16(Wrec * mask), 4 col-tiles x 8 k-chunks ---
    bf16x8 Bf[4][8];
    #pragma unroll
    for (int tc = 0; tc < 4; ++tc) {
        const int n = n0 + tc * 16 + l15;
        #pragma unroll
        for (int kk = 0; kk < 8; ++kk)
            Bf[tc][kk] = load_bfrag(Wrec, mask, (size_t)n * H_ + kk * 32 + quad * 8);
    }
    // --- fused-projection fragments (optional) ---
    bf16x8 Bf2[4][8];
    float  b2[4];
    if (Wf) {
        #pragma unroll
        for (int tc = 0; tc < 4; ++tc) {
            const int n = n0 + tc * 16 + l15;
            b2[tc] = bf[n];
            #pragma unroll
            for (int kk = 0; kk < 8; ++kk)
                Bf2[tc][kk] = load_bfrag(Wf, nullptr, (size_t)n * H_ + kk * 32 + quad * 8);
        }
    }

    // --- per-lane epilogue state: 4 tiles x 2 regs ---
    const int bg = blockIdx.x * 8;
    float inv_tau[4], h_prev[4][2], xp_cur[4][2], xp_nxt[4][2];
    #pragma unroll
    for (int tc = 0; tc < 4; ++tc) {
        const int c = n0 + tc * 16 + l15;
        inv_tau[tc] = 1.0f / (logf(1.0f + __expf(tau_raw[c])) + 0.1f);
        #pragma unroll
        for (int reg = 0; reg < 2; ++reg) {
            const int b = bg + quad * 2 + reg;
            h_prev[tc][reg] = 0.0f;
            xp_cur[tc][reg] = xp[(size_t)(b * T_) * xp_stride + xp_col + c];
            xp_nxt[tc][reg] = 0.0f;
        }
    }

    // zero BOTH h buffers (garbage A-slots must stay zero forever)
    for (int i = tid; i < 2 * 16 * LP / 2; i += 256)
        ((unsigned int*)&hb16[0][0][0])[i] = 0u;
    __syncthreads();   // full barrier once (prologue)

    for (int t = 0; t <= T_; ++t) {
        const int rb = t & 1;   // hb16[rb] holds h(t-1)

        // A fragments (shared by recurrence and fused projection)
        bf16x8 Af[8];
        #pragma unroll
        for (int kk = 0; kk < 8; ++kk)
            Af[kk] = *(const bf16x8*)&hb16[rb][l15][kk * 32 + quad * 8];

        if (t < T_) {
            // prefetch xp(t+1)
            if (t + 1 < T_) {
                #pragma unroll
                for (int tc = 0; tc < 4; ++tc)
                    #pragma unroll
                    for (int reg = 0; reg < 2; ++reg) {
                        const int b = bg + quad * 2 + reg;
                        xp_nxt[tc][reg] =
                            xp[(size_t)(b * T_ + t + 1) * xp_stride + xp_col
                               + n0 + tc * 16 + l15];
                    }
            }

            f32x4 acc[4] = {{0,0,0,0},{0,0,0,0},{0,0,0,0},{0,0,0,0}};
            #pragma unroll
            for (int kk = 0; kk < 8; ++kk)
                #pragma unroll
                for (int tc = 0; tc < 4; ++tc)
                    acc[tc] = __builtin_amdgcn_mfma_f32_16x16x32_bf16(
                        Af[kk], Bf[tc][kk], acc[tc], 0, 0, 0);

            // epilogue: h update, LDS bf16 write, scatter global store
            #pragma unroll
            for (int tc = 0; tc < 4; ++tc) {
                const int c = n0 + tc * 16 + l15;
                #pragma unroll
                for (int reg = 0; reg < 2; ++reg) {
                    const int b   = bg + quad * 2 + reg;
                    const float pre = xp_cur[tc][reg] + acc[tc][reg];
                    const float hn  = h_prev[tc][reg]
                                    + (fast_tanh(pre) - h_prev[tc][reg]) * inv_tau[tc];
                    h_prev[tc][reg] = hn;
                    hb16[rb ^ 1][quad * 4 + reg][c] = f2bf(hn);
                    hout[(size_t)(b * T_ + t) * out_stride + out_col + c] = hn;
                    xp_cur[tc][reg] = xp_nxt[tc][reg];
                }
            }
        }

        // fused projection: xp1(t-1) = h0(t-1) @ W_in1^T + b1
        if (Wf && t > 0) {
            f32x4 acc2[4];
            #pragma unroll
            for (int tc = 0; tc < 4; ++tc)
                acc2[tc] = (f32x4){b2[tc], b2[tc], b2[tc], b2[tc]};
            #pragma unroll
            for (int kk = 0; kk < 8; ++kk)
                #pragma unroll
                for (int tc = 0; tc < 4; ++tc)
                    acc2[tc] = __builtin_amdgcn_mfma_f32_16x16x32_bf16(
                        Af[kk], Bf2[tc][kk], acc2[tc], 0, 0, 0);
            #pragma unroll
            for (int tc = 0; tc < 4; ++tc) {
                const int c = n0 + tc * 16 + l15;
                #pragma unroll
                for (int reg = 0; reg < 2; ++reg) {
                    const int b = bg + quad * 2 + reg;
                    xf[(size_t)(b * T_ + t - 1) * H_ + c] = acc2[tc][reg];
                }
            }
        }

        if (t < T_) LGKM_BARRIER();
    }
}

// ---------------------------------------------------------------------------
// Proj: dst[r][dst_col+n] = bias[n] + sum_k src_row(r)[src_col+k] * Wi[n][k]
// 256 WGs x 32 rows, 512 threads (8 waves). Wave owns 2 col-tiles (64 B-regs);
// 32 rows staged to LDS as bf16; row-tiles processed sequentially (no
// Af[2][8] double-buffer -> ~140 VGPR, no spill at launch_bounds(512,2)).
// ---------------------------------------------------------------------------
__global__ __launch_bounds__(512, 2)
void proj_mfma(const float* __restrict__ src, int src_stride, int src_col,
               const int* __restrict__ tok,
               const float* __restrict__ Wi,
               const float* __restrict__ bias,
               float* __restrict__ dst, int dst_stride, int dst_col)
{
    const int tid  = threadIdx.x;
    const int lane = tid & 63;
    const int wv   = tid >> 6;     // 0..7 -> 2 col-tiles each
    const int quad = lane >> 4;
    const int l15  = lane & 15;
    const int n0   = wv * 32;

    __shared__ __align__(16) ushort_t As[32][LP];

    bf16x8 Bf[2][8];
    float  bj[2];
    #pragma unroll
    for (int tc = 0; tc < 2; ++tc) {
        const int n = n0 + tc * 16 + l15;
        bj[tc] = bias[n];
        #pragma unroll
        for (int kk = 0; kk < 8; ++kk)
            Bf[tc][kk] = load_bfrag(Wi, nullptr, (size_t)n * H_ + kk * 32 + quad * 8);
    }

    const int r0 = blockIdx.x * 32;
    // stage 32 rows x 256 f32 -> bf16: 512 threads x 16 elements
    {
        const int row = tid >> 4;          // 0..31
        const int seg = tid & 15;          // 16-element chunk
        const size_t sb = (tok ? (size_t)tok[r0 + row] : (size_t)(r0 + row))
                          * src_stride + src_col + seg * 16;
        union { uint4 q[2]; ushort_t u[16]; } p;
        #pragma unroll
        for (int h = 0; h < 2; ++h) {
            float4 f0 = *(const float4*)(src + sb + h * 8);
            float4 f1 = *(const float4*)(src + sb + h * 8 + 4);
            p.u[h*8+0] = f2bf(f0.x); p.u[h*8+1] = f2bf(f0.y);
            p.u[h*8+2] = f2bf(f0.z); p.u[h*8+3] = f2bf(f0.w);
            p.u[h*8+4] = f2bf(f1.x); p.u[h*8+5] = f2bf(f1.y);
            p.u[h*8+6] = f2bf(f1.z); p.u[h*8+7] = f2bf(f1.w);
        }
        *(uint4*)&As[row][seg * 16]     = p.q[0];
        *(uint4*)&As[row][seg * 16 + 8] = p.q[1];
    }
    __syncthreads();

    #pragma unroll
    for (int rt = 0; rt < 2; ++rt) {
        bf16x8 Af[8];
        #pragma unroll
        for (int kk = 0; kk < 8; ++kk)
            Af[kk] = *(const bf16x8*)&As[rt * 16 + l15][kk * 32 + quad * 8];

        f32x4 acc[2] = {{bj[0],bj[0],bj[0],bj[0]}, {bj[1],bj[1],bj[1],bj[1]}};
        #pragma unroll
        for (int kk = 0; kk < 8; ++kk)
            #pragma unroll
            for (int tc = 0; tc < 2; ++tc)
                acc[tc] = __builtin_amdgcn_mfma_f32_16x16x32_bf16(
                    Af[kk], Bf[tc][kk], acc[tc], 0, 0, 0);

        #pragma unroll
        for (int tc = 0; tc < 2; ++tc) {
            const int c = n0 + tc * 16 + l15;
            #pragma unroll
            for (int reg = 0; reg < 4; ++reg) {
                const int r = r0 + rt * 16 + quad * 4 + reg;
                dst[(size_t)r * dst_stride + dst_col + c] = acc[tc][reg];
            }
        }
    }
}

extern "C" void kernel_launch(void* const* d_in, const int* in_sizes, int n_in,
                              void* d_out, int out_size, void* d_ws, size_t ws_size,
                              hipStream_t stream)
{
    const int*   tokens = (const int*)d_in[0];
    const float* emb    = (const float*)d_in[1];
    const float* W_in0  = (const float*)d_in[2];
    const float* W_rec0 = (const float*)d_in[3];
    const float* b0     = (const float*)d_in[4];
    const float* tau0   = (const float*)d_in[5];
    const float* mask0  = (const float*)d_in[6];
    const float* W_in1  = (const float*)d_in[7];
    const float* W_rec1 = (const float*)d_in[8];
    const float* b1     = (const float*)d_in[9];
    const float* tau1   = (const float*)d_in[10];
    const float* mask1  = (const float*)d_in[11];
    float* out = (float*)d_out;    // [8192, 512] f32
    float* ws  = (float*)d_ws;     // xp1 scratch [B,T,H] if big enough
    (void)in_sizes; (void)n_in; (void)out_size;

    const bool fused = ws_size >= (size_t)B_ * T_ * H_ * sizeof(float);

    // cols 0..255 of out: h0 (final L0 output). cols 256..511: xp0, then h1.
    proj_mfma<<<dim3(256), dim3(512), 0, stream>>>(
        emb, E_, 0, tokens, W_in0, b0, out, OW_, H_);

    ltc_scan_mfma<<<dim3(8), dim3(256), 0, stream>>>(
        out, OW_, H_,      // xp0 in cols 256..511
        out, OW_, 0,       // h0 -> cols 0..255
        W_rec0, mask0, tau0,
        fused ? W_in1 : nullptr, fused ? b1 : nullptr, fused ? ws : nullptr);

    if (fused) {
        ltc_scan_mfma<<<dim3(8), dim3(256), 0, stream>>>(
            ws, H_, 0,     // xp1 from workspace
            out, OW_, H_,  // h1 -> cols 256..511
            W_rec1, mask1, tau1, nullptr, nullptr, nullptr);
    } else {
        proj_mfma<<<dim3(256), dim3(512), 0, stream>>>(
            out, OW_, 0, nullptr, W_in1, b1, out, OW_, H_);
        ltc_scan_mfma<<<dim3(8), dim3(256), 0, stream>>>(
            out, OW_, H_,  // xp1 in cols 256..511 (aliases h1 - r7-safe)
            out, OW_, H_,
            W_rec1, mask1, tau1, nullptr, nullptr, nullptr);
    }
}

// Round 9
// 277.494 us; speedup vs baseline: 1.9861x; 1.4772x over previous
//
#include <hip/hip_runtime.h>
#include <hip/hip_bf16.h>

#define B_ 64
#define T_ 128
#define E_ 256
#define H_ 256
#define OW_ 512   // output row width = 2*H (elements)
#define LP 264    // LDS bf16 row pitch (elements)
#define MAGIC 0x5AD00000u

typedef unsigned short ushort_t;
typedef __attribute__((ext_vector_type(8))) short bf16x8;   // 8 bf16 = 4 VGPRs
typedef __attribute__((ext_vector_type(4))) float f32x4;    // 4 f32 acc

// Workgroup barrier WITHOUT the compiler's vmcnt(0) drain (validated r7/r8).
#define LGKM_BARRIER() asm volatile("s_waitcnt lgkmcnt(0)\n\ts_barrier" ::: "memory")

__device__ __forceinline__ ushort_t f2bf(float f) {
    unsigned int x = __float_as_uint(f);
    unsigned int r = x + 0x7FFFu + ((x >> 16) & 1u);
    return (ushort_t)(r >> 16);
}
__device__ __forceinline__ float fast_tanh(float x) {
    float e = __expf(2.0f * x);
    return 1.0f - 2.0f * __builtin_amdgcn_rcpf(e + 1.0f);
}
__device__ __forceinline__ bf16x8 load_bfrag(const float* W, const float* M,
                                             size_t base) {
    float4 a = *(const float4*)(W + base);
    float4 b = *(const float4*)(W + base + 4);
    if (M) {
        float4 ma = *(const float4*)(M + base);
        float4 mb = *(const float4*)(M + base + 4);
        a.x *= ma.x; a.y *= ma.y; a.z *= ma.z; a.w *= ma.w;
        b.x *= mb.x; b.y *= mb.y; b.z *= mb.z; b.w *= mb.w;
    }
    union { bf16x8 v; ushort_t u[8]; } r;
    r.u[0] = f2bf(a.x); r.u[1] = f2bf(a.y); r.u[2] = f2bf(a.z); r.u[3] = f2bf(a.w);
    r.u[4] = f2bf(b.x); r.u[5] = f2bf(b.y); r.u[6] = f2bf(b.z); r.u[7] = f2bf(b.w);
    return r.v;
}

// ---------------------------------------------------------------------------
// scan_core<FUSE,WAIT>: one batch group (8 rows), 512 threads (8 waves x 32
// cols = 2 MFMA col-tiles/wave). Batch row i at LDS A-slot (i>>1)*4+(i&1)
// (slots {0,1,4,5,8,9,12,13}); C rows quad*4+reg valid for reg<2 ->
// lane(quad,l15) owns batches {quad*2, quad*2+1} x cols {n0+tc*16+l15}.
// FUSE: also computes xp1(t-1) = h0(t-1) @ Wf^T + bf with the same A-frags,
//   stores it agent-scope (cross-XCD visible), publishes 8-row chunks via
//   vmcnt-draining __syncthreads + release flag.
// WAIT: spins (acquire, poison-tolerant window) for each 8-row xp chunk.
// Neither: standalone (fallback); alias-safe (reads row t+2, writes row t).
// MFMA 16x16x32 layouts verified r5-r8.
// ---------------------------------------------------------------------------
template<bool FUSE, bool WAIT>
__device__ __forceinline__ void scan_core(
    int grp, ushort_t (*hb16)[16][LP],
    const float* xp, int xp_stride, int xp_col,
    float* hout, int out_col,
    const float* Wrec, const float* Wmask, const float* tau_raw,
    const float* Wf, const float* bfv, float* xf,
    unsigned int* flag)
{
    const int tid  = threadIdx.x;
    const int lane = tid & 63;
    const int wv   = tid >> 6;     // 0..7
    const int quad = lane >> 4;
    const int l15  = lane & 15;
    const int n0   = wv * 32;
    const int bg   = grp * 8;

    bf16x8 Bf[2][8];
    #pragma unroll
    for (int tc = 0; tc < 2; ++tc)
        #pragma unroll
        for (int kk = 0; kk < 8; ++kk)
            Bf[tc][kk] = load_bfrag(Wrec, Wmask,
                (size_t)(n0 + tc * 16 + l15) * H_ + kk * 32 + quad * 8);

    bf16x8 Bf2[2][8];
    float  b2[2] = {0.f, 0.f};
    if (FUSE) {
        #pragma unroll
        for (int tc = 0; tc < 2; ++tc) {
            b2[tc] = bfv[n0 + tc * 16 + l15];
            #pragma unroll
            for (int kk = 0; kk < 8; ++kk)
                Bf2[tc][kk] = load_bfrag(Wf, nullptr,
                    (size_t)(n0 + tc * 16 + l15) * H_ + kk * 32 + quad * 8);
        }
    }

    float inv_tau[2], h_prev[2][2];
    float xp_c[2][2], xp_n[2][2], xp_nn[2][2];
    #pragma unroll
    for (int tc = 0; tc < 2; ++tc) {
        inv_tau[tc] = 1.0f / (logf(1.0f + __expf(tau_raw[n0 + tc * 16 + l15])) + 0.1f);
        #pragma unroll
        for (int reg = 0; reg < 2; ++reg) {
            h_prev[tc][reg] = 0.0f;
            xp_c[tc][reg] = xp_n[tc][reg] = xp_nn[tc][reg] = 0.0f;
        }
    }

    if (!WAIT) {   // prologue loads for t=0,1 (WAIT loads at chunk tops)
        #pragma unroll
        for (int tc = 0; tc < 2; ++tc)
            #pragma unroll
            for (int reg = 0; reg < 2; ++reg) {
                const int b = bg + quad * 2 + reg;
                const int c = n0 + tc * 16 + l15;
                xp_c[tc][reg] = xp[(size_t)(b * T_ + 0) * xp_stride + xp_col + c];
                xp_n[tc][reg] = xp[(size_t)(b * T_ + 1) * xp_stride + xp_col + c];
            }
    }

    for (int i = tid; i < 2 * 16 * LP / 2; i += 512)
        ((unsigned int*)&hb16[0][0][0])[i] = 0u;
    __syncthreads();

    const int tmax = FUSE ? T_ : (T_ - 1);
    for (int t = 0; t <= tmax; ++t) {
        const int rb = t & 1;

        if (WAIT && t < T_ && (t & 7) == 0) {
            if (tid == 0) {
                const unsigned need = (unsigned)(t >> 3) + 1u;
                for (;;) {
                    unsigned d = __hip_atomic_load(flag, __ATOMIC_ACQUIRE,
                                                   __HIP_MEMORY_SCOPE_AGENT) - MAGIC;
                    if (d >= need && d <= 16u) break;
                    __builtin_amdgcn_s_sleep(2);
                }
            }
            __syncthreads();
            #pragma unroll
            for (int tc = 0; tc < 2; ++tc)
                #pragma unroll
                for (int reg = 0; reg < 2; ++reg) {
                    const int b = bg + quad * 2 + reg;
                    xp_c[tc][reg] = xp[(size_t)(b * T_ + t) * xp_stride + xp_col
                                       + n0 + tc * 16 + l15];
                }
        }

        // A fragments (h(t-1)); shared by recurrence and fused projection
        bf16x8 Af[8];
        #pragma unroll
        for (int kk = 0; kk < 8; ++kk)
            Af[kk] = *(const bf16x8*)&hb16[rb][l15][kk * 32 + quad * 8];

        if (t < T_) {
            // prefetch
            if (WAIT) {
                if ((t & 7) != 7 && t + 1 < T_) {
                    #pragma unroll
                    for (int tc = 0; tc < 2; ++tc)
                        #pragma unroll
                        for (int reg = 0; reg < 2; ++reg) {
                            const int b = bg + quad * 2 + reg;
                            xp_n[tc][reg] = xp[(size_t)(b * T_ + t + 1) * xp_stride
                                               + xp_col + n0 + tc * 16 + l15];
                        }
                }
            } else if (t + 2 < T_) {
                #pragma unroll
                for (int tc = 0; tc < 2; ++tc)
                    #pragma unroll
                    for (int reg = 0; reg < 2; ++reg) {
                        const int b = bg + quad * 2 + reg;
                        xp_nn[tc][reg] = xp[(size_t)(b * T_ + t + 2) * xp_stride
                                            + xp_col + n0 + tc * 16 + l15];
                    }
            }

            f32x4 acc[2] = {{0.f,0.f,0.f,0.f},{0.f,0.f,0.f,0.f}};
            #pragma unroll
            for (int kk = 0; kk < 8; ++kk)
                #pragma unroll
                for (int tc = 0; tc < 2; ++tc)
                    acc[tc] = __builtin_amdgcn_mfma_f32_16x16x32_bf16(
                        Af[kk], Bf[tc][kk], acc[tc], 0, 0, 0);

            #pragma unroll
            for (int tc = 0; tc < 2; ++tc) {
                const int c = n0 + tc * 16 + l15;
                #pragma unroll
                for (int reg = 0; reg < 2; ++reg) {
                    const int b = bg + quad * 2 + reg;
                    const float pre = xp_c[tc][reg] + acc[tc][reg];
                    const float hn  = h_prev[tc][reg]
                                    + (fast_tanh(pre) - h_prev[tc][reg]) * inv_tau[tc];
                    h_prev[tc][reg] = hn;
                    hb16[rb ^ 1][quad * 4 + reg][c] = f2bf(hn);
                    hout[(size_t)(b * T_ + t) * OW_ + out_col + c] = hn;
                }
            }
            if (WAIT) {
                if ((t & 7) != 7) {
                    #pragma unroll
                    for (int tc = 0; tc < 2; ++tc)
                        #pragma unroll
                        for (int reg = 0; reg < 2; ++reg)
                            xp_c[tc][reg] = xp_n[tc][reg];
                }
            } else {
                #pragma unroll
                for (int tc = 0; tc < 2; ++tc)
                    #pragma unroll
                    for (int reg = 0; reg < 2; ++reg) {
                        xp_c[tc][reg] = xp_n[tc][reg];
                        xp_n[tc][reg] = xp_nn[tc][reg];
                    }
            }
        }

        if (FUSE && t > 0) {
            f32x4 acc2[2];
            #pragma unroll
            for (int tc = 0; tc < 2; ++tc)
                acc2[tc] = (f32x4){b2[tc], b2[tc], b2[tc], b2[tc]};
            #pragma unroll
            for (int kk = 0; kk < 8; ++kk)
                #pragma unroll
                for (int tc = 0; tc < 2; ++tc)
                    acc2[tc] = __builtin_amdgcn_mfma_f32_16x16x32_bf16(
                        Af[kk], Bf2[tc][kk], acc2[tc], 0, 0, 0);
            #pragma unroll
            for (int tc = 0; tc < 2; ++tc) {
                const int c = n0 + tc * 16 + l15;
                #pragma unroll
                for (int reg = 0; reg < 2; ++reg) {
                    const int b = bg + quad * 2 + reg;
                    // agent-scope store: cross-XCD visible once retired
                    __hip_atomic_store(&xf[(size_t)(b * T_ + t - 1) * H_ + c],
                                       acc2[tc][reg],
                                       __ATOMIC_RELAXED, __HIP_MEMORY_SCOPE_AGENT);
                }
            }
        }

        if (FUSE && t > 0 && (t & 7) == 0) {
            __syncthreads();   // drains vmcnt -> all xf stores of rows < t retired
            if (tid == 0)
                __hip_atomic_store(flag, MAGIC + (unsigned)(t >> 3),
                                   __ATOMIC_RELEASE, __HIP_MEMORY_SCOPE_AGENT);
        } else if (t < tmax) {
            LGKM_BARRIER();
        }
    }
}

// Single dispatch: WGs 0..7 = level-0 producers (scan0 + fused xp1),
// WGs 8..15 = level-1 consumers (scan1), pipelined 8 steps behind.
__global__ __launch_bounds__(512, 2)
void ltc_dual(float* out,
              const float* __restrict__ Wr0, const float* __restrict__ m0,
              const float* __restrict__ t0,
              const float* __restrict__ Wi1, const float* __restrict__ b1v,
              const float* __restrict__ Wr1, const float* __restrict__ m1,
              const float* __restrict__ t1,
              float* xf, unsigned int* flags)
{
    __shared__ __align__(16) ushort_t hb16[2][16][LP];
    if (blockIdx.x < 8)
        scan_core<true, false>(blockIdx.x, hb16,
                               out, OW_, H_,     // xp0 in out cols 256..511
                               out, 0,           // h0 -> cols 0..255
                               Wr0, m0, t0, Wi1, b1v, xf, flags + blockIdx.x);
    else
        scan_core<false, true>(blockIdx.x - 8, hb16,
                               xf, H_, 0,        // xp1 from workspace
                               out, H_,          // h1 -> cols 256..511
                               Wr1, m1, t1, nullptr, nullptr, nullptr,
                               flags + blockIdx.x - 8);
}

// Fallback standalone scan (no workspace): r8-proven aliased path.
__global__ __launch_bounds__(512, 2)
void ltc_single(const float* xp, int xp_stride, int xp_col,
                float* hout, int out_col,
                const float* __restrict__ Wr, const float* __restrict__ mk,
                const float* __restrict__ tu)
{
    __shared__ __align__(16) ushort_t hb16[2][16][LP];
    scan_core<false, false>(blockIdx.x, hb16, xp, xp_stride, xp_col,
                            hout, out_col, Wr, mk, tu,
                            nullptr, nullptr, nullptr, nullptr);
}

// ---------------------------------------------------------------------------
// Proj (unchanged from r8, passing): dst[r][dst_col+n] = bias[n] + src@Wi^T
// ---------------------------------------------------------------------------
__global__ __launch_bounds__(512, 2)
void proj_mfma(const float* __restrict__ src, int src_stride, int src_col,
               const int* __restrict__ tok,
               const float* __restrict__ Wi,
               const float* __restrict__ bias,
               float* __restrict__ dst, int dst_stride, int dst_col)
{
    const int tid  = threadIdx.x;
    const int lane = tid & 63;
    const int wv   = tid >> 6;
    const int quad = lane >> 4;
    const int l15  = lane & 15;
    const int n0   = wv * 32;

    __shared__ __align__(16) ushort_t As[32][LP];

    bf16x8 Bf[2][8];
    float  bj[2];
    #pragma unroll
    for (int tc = 0; tc < 2; ++tc) {
        const int n = n0 + tc * 16 + l15;
        bj[tc] = bias[n];
        #pragma unroll
        for (int kk = 0; kk < 8; ++kk)
            Bf[tc][kk] = load_bfrag(Wi, nullptr, (size_t)n * H_ + kk * 32 + quad * 8);
    }

    const int r0 = blockIdx.x * 32;
    {
        const int row = tid >> 4;
        const int seg = tid & 15;
        const size_t sb = (tok ? (size_t)tok[r0 + row] : (size_t)(r0 + row))
                          * src_stride + src_col + seg * 16;
        union { uint4 q[2]; ushort_t u[16]; } p;
        #pragma unroll
        for (int h = 0; h < 2; ++h) {
            float4 f0 = *(const float4*)(src + sb + h * 8);
            float4 f1 = *(const float4*)(src + sb + h * 8 + 4);
            p.u[h*8+0] = f2bf(f0.x); p.u[h*8+1] = f2bf(f0.y);
            p.u[h*8+2] = f2bf(f0.z); p.u[h*8+3] = f2bf(f0.w);
            p.u[h*8+4] = f2bf(f1.x); p.u[h*8+5] = f2bf(f1.y);
            p.u[h*8+6] = f2bf(f1.z); p.u[h*8+7] = f2bf(f1.w);
        }
        *(uint4*)&As[row][seg * 16]     = p.q[0];
        *(uint4*)&As[row][seg * 16 + 8] = p.q[1];
    }
    __syncthreads();

    #pragma unroll
    for (int rt = 0; rt < 2; ++rt) {
        bf16x8 Af[8];
        #pragma unroll
        for (int kk = 0; kk < 8; ++kk)
            Af[kk] = *(const bf16x8*)&As[rt * 16 + l15][kk * 32 + quad * 8];

        f32x4 acc[2] = {{bj[0],bj[0],bj[0],bj[0]}, {bj[1],bj[1],bj[1],bj[1]}};
        #pragma unroll
        for (int kk = 0; kk < 8; ++kk)
            #pragma unroll
            for (int tc = 0; tc < 2; ++tc)
                acc[tc] = __builtin_amdgcn_mfma_f32_16x16x32_bf16(
                    Af[kk], Bf[tc][kk], acc[tc], 0, 0, 0);

        #pragma unroll
        for (int tc = 0; tc < 2; ++tc) {
            const int c = n0 + tc * 16 + l15;
            #pragma unroll
            for (int reg = 0; reg < 4; ++reg) {
                const int r = r0 + rt * 16 + quad * 4 + reg;
                dst[(size_t)r * dst_stride + dst_col + c] = acc[tc][reg];
            }
        }
    }
}

extern "C" void kernel_launch(void* const* d_in, const int* in_sizes, int n_in,
                              void* d_out, int out_size, void* d_ws, size_t ws_size,
                              hipStream_t stream)
{
    const int*   tokens = (const int*)d_in[0];
    const float* emb    = (const float*)d_in[1];
    const float* W_in0  = (const float*)d_in[2];
    const float* W_rec0 = (const float*)d_in[3];
    const float* b0     = (const float*)d_in[4];
    const float* tau0   = (const float*)d_in[5];
    const float* mask0  = (const float*)d_in[6];
    const float* W_in1  = (const float*)d_in[7];
    const float* W_rec1 = (const float*)d_in[8];
    const float* b1     = (const float*)d_in[9];
    const float* tau1   = (const float*)d_in[10];
    const float* mask1  = (const float*)d_in[11];
    float* out = (float*)d_out;    // [8192, 512] f32
    (void)in_sizes; (void)n_in; (void)out_size;

    const size_t xf_elems = (size_t)B_ * T_ * H_;
    const bool pipelined = ws_size >= xf_elems * sizeof(float) + 64;

    // proj0: emb-gather GEMM -> xp0 in out cols 256..511
    proj_mfma<<<dim3(256), dim3(512), 0, stream>>>(
        emb, E_, 0, tokens, W_in0, b0, out, OW_, H_);

    if (pipelined) {
        float* xf = (float*)d_ws;
        unsigned int* flags = (unsigned int*)((float*)d_ws + xf_elems);
        // flags arrive poisoned (0xAA..) each launch; consumers' window check
        // treats poison as not-ready; producers overwrite with MAGIC+c.
        ltc_dual<<<dim3(16), dim3(512), 0, stream>>>(
            out, W_rec0, mask0, tau0, W_in1, b1, W_rec1, mask1, tau1, xf, flags);
    } else {
        ltc_single<<<dim3(8), dim3(512), 0, stream>>>(
            out, OW_, H_, out, 0, W_rec0, mask0, tau0);
        proj_mfma<<<dim3(256), dim3(512), 0, stream>>>(
            out, OW_, 0, nullptr, W_in1, b1, out, OW_, H_);
        ltc_single<<<dim3(8), dim3(512), 0, stream>>>(
            out, OW_, H_, out, H_, W_rec1, mask1, tau1);
    }
}